// Round 13
// baseline (174.167 us; speedup 1.0000x reference)
//
#include <hip/hip_runtime.h>
#include <hip/hip_bf16.h>
#include <math.h>

#define NPTS 4096
#define KNB 16
#define CAP 384
#define QPB 4   // points (=knn queries) per block

typedef __attribute__((ext_vector_type(8))) short bf16x8;
typedef __attribute__((ext_vector_type(4))) float f32x4;
#define MFMA16(a, b, c) __builtin_amdgcn_mfma_f32_16x16x32_bf16(a, b, c, 0, 0, 0)

__device__ __forceinline__ unsigned short f2bf(float f) {
  unsigned int u = __float_as_uint(f);
  unsigned int r = (u + 0x7fffu + ((u >> 16) & 1u)) >> 16;
  return (unsigned short)r;
}

// ---------------------------------------------------------------------------
// Kernel 1 "qkv_pack" (unchanged from R12):
//   blocks [0,128)   qkv = x @ w_qkv + b_qkv via MFMA (64 rows/block, no LDS)
//   blocks [128,272) pack w_a1/w_a2/w_p2 -> bf16 MFMA B-frag order
//   block 272        zero stats
// ---------------------------------------------------------------------------
__global__ __launch_bounds__(256) void qkv_pack_kernel(
    const float* __restrict__ x, const float* __restrict__ w_qkv,
    const float* __restrict__ b_qkv, float* __restrict__ qkv,
    const float* __restrict__ w_a1, const float* __restrict__ w_a2,
    const float* __restrict__ w_p2, unsigned short* __restrict__ pk1,
    unsigned short* __restrict__ pk2, unsigned short* __restrict__ pkp,
    float* __restrict__ stats) {
  int tid = threadIdx.x, bid = blockIdx.x;

  if (bid == 272) {
    if (tid < 128) stats[tid] = 0.f;
    return;
  }
  if (bid >= 128) {
    int e = (bid - 128) * 256 + tid;
    if (e < 16384) {  // w_a1 [64][256]: KS=2, NT=16
      int j = e & 7, lane = (e >> 3) & 63, t = e >> 9;
      int ks = t & 1, nt = t >> 1;
      int k = ks * 32 + ((lane >> 4) << 3) + j, n = nt * 16 + (lane & 15);
      pk1[e] = f2bf(w_a1[k * 256 + n]);
    } else if (e < 32768) {  // w_a2 [256][64]: KS=8, NT=4
      int e2 = e - 16384;
      int j = e2 & 7, lane = (e2 >> 3) & 63, t = e2 >> 9;
      int ks = t & 7, nt = t >> 3;
      int k = ks * 32 + ((lane >> 4) << 3) + j, n = nt * 16 + (lane & 15);
      pk2[e2] = f2bf(w_a2[k * 64 + n]);
    } else if (e < 36864) {  // w_p2 [64][64]: KS=2, NT=4
      int e3 = e - 32768;
      int j = e3 & 7, lane = (e3 >> 3) & 63, t = e3 >> 9;
      int ks = t & 1, nt = t >> 1;
      int k = ks * 32 + ((lane >> 4) << 3) + j, n = nt * 16 + (lane & 15);
      pkp[e3] = f2bf(w_p2[k * 64 + n]);
    }
    return;
  }

  // qkv MFMA: wave w -> rows r0w..r0w+15
  int lane = tid & 63, w = tid >> 6;
  int m = lane & 15, quad = lane >> 4;
  int r0w = bid * 64 + w * 16;

  const float* xr = x + (size_t)(r0w + m) * 64;
  float xa[8], xb[8];
  *(float4*)&xa[0] = *(const float4*)(xr + quad * 8);
  *(float4*)&xa[4] = *(const float4*)(xr + quad * 8 + 4);
  *(float4*)&xb[0] = *(const float4*)(xr + 32 + quad * 8);
  *(float4*)&xb[4] = *(const float4*)(xr + 32 + quad * 8 + 4);
  bf16x8 a0, a1;
#pragma unroll
  for (int j = 0; j < 8; ++j) {
    a0[j] = (short)f2bf(xa[j]);
    a1[j] = (short)f2bf(xb[j]);
  }

#pragma unroll 4
  for (int nt = 0; nt < 12; ++nt) {
    int n = nt * 16 + m;
    int k0 = quad * 8;
    bf16x8 b0, b1;
#pragma unroll
    for (int j = 0; j < 8; ++j) {
      b0[j] = (short)f2bf(w_qkv[(size_t)(k0 + j) * 192 + n]);
      b1[j] = (short)f2bf(w_qkv[(size_t)(32 + k0 + j) * 192 + n]);
    }
    f32x4 acc = {0.f, 0.f, 0.f, 0.f};
    acc = MFMA16(a0, b0, acc);
    acc = MFMA16(a1, b1, acc);
    float bb = b_qkv[n];
#pragma unroll
    for (int i = 0; i < 4; ++i)
      qkv[(size_t)(r0w + quad * 4 + i) * 192 + n] = acc[i] + bb;
  }
}

// ---------------------------------------------------------------------------
// Kernel 2 "fused" (v4): QPB=4, grid 2048 -> 8 blocks/CU supply.
// LDS ~12.5 KB (KNN scratch 12.4 KB aliased with attention 10 KB).
// One wave = one point (16 (k) rows). One-pass KNN -> s_idx, MFMA attention,
// v in 16 VGPRs, fc + stats. __launch_bounds__(256,4): VGPR cap 128 (no
// tighter cap — R11 spill lesson); expect allocator ~56-64 -> 8 blocks/CU.
// ---------------------------------------------------------------------------
__global__ __launch_bounds__(256, 4) void fused_kernel(
    const float* __restrict__ qkv, const float* __restrict__ pos,
    const unsigned short* __restrict__ pk1,
    const unsigned short* __restrict__ pk2,
    const unsigned short* __restrict__ pkp, const float* __restrict__ w_p1,
    const float* __restrict__ b_p1, const float* __restrict__ b_p2,
    const float* __restrict__ b_a1, const float* __restrict__ b_a2,
    const float* __restrict__ w_fc, const float* __restrict__ b_fc,
    float* __restrict__ y, float* __restrict__ stats) {
  __shared__ __align__(16) char smem[12544];
  __shared__ int s_idx[64];

  int tid = threadIdx.x, lane = tid & 63, w = tid >> 6;
  int m = lane & 15, quad = lane >> 4;
  int g0 = blockIdx.x * QPB;
  int b = g0 >> 12;
  const float* posb = pos + (size_t)b * NPTS * 3;

  // ======================= KNN phase =======================
  {
    unsigned int(*cbits)[CAP] = (unsigned int(*)[CAP])smem;            // 6144
    int(*cidx)[CAP] = (int(*)[CAP])(smem + 6144);                      // 6144
    unsigned long long* wmin = (unsigned long long*)(smem + 12288);    // 32
    float* sretry = (float*)(smem + 12320);                            // 16
    unsigned int* scnt = (unsigned int*)(smem + 12336);                // 16
    unsigned long long* sprev = (unsigned long long*)(smem + 12352);   // 8
    int* sany = (int*)(smem + 12360);                                  // 4

    float qx[QPB], qy[QPB], qz[QPB];
#pragma unroll
    for (int q = 0; q < QPB; ++q) {
      int i = (g0 + q) & (NPTS - 1);
      qx[q] = posb[i * 3 + 0];
      qy[q] = posb[i * 3 + 1];
      qz[q] = posb[i * 3 + 2];
    }
    if (tid < QPB) scnt[tid] = 0;
    if (tid == 0) sany[0] = 0;
    __syncthreads();

    const float T2 = 0.015625f;  // d < 0.125; expected count ~33
    for (int c = 0; c < NPTS / 256; ++c) {
      int j = c * 256 + tid;
      int j3 = j * 3;
      float px = posb[j3 + 0], py = posb[j3 + 1], pz = posb[j3 + 2];
#pragma unroll
      for (int q = 0; q < QPB; ++q) {
        float dx = qx[q] - px, dy = qy[q] - py, dz = qz[q] - pz;
        float d2 = fmaf(dz, dz, fmaf(dy, dy, dx * dx));
        bool hit = d2 < T2;
        unsigned long long mask = __ballot(hit);
        if (mask) {  // wave-uniform skip
          if (hit) {
            unsigned int p = atomicAdd(&scnt[q], 1u);
            if (p < CAP) {
              cbits[q][p] = __float_as_uint(d2);
              cidx[q][p] = j;
            }
          }
        }
      }
    }
    __syncthreads();

    if (tid < QPB) {
      int q = tid;
      unsigned int n = scnt[q];
      float nt = 0.f;
      if (n < KNB) nt = 0.0625f;            // widen: d < 0.25
      else if (n > CAP) nt = 0.00390625f;   // narrow: d < 0.0625
      sretry[q] = nt;
      if (nt != 0.f) {
        scnt[q] = 0;
        sany[0] = 1;
      }
    }
    __syncthreads();

    if (sany[0]) {  // rare; block-uniform
      float tr[QPB];
#pragma unroll
      for (int q = 0; q < QPB; ++q) tr[q] = sretry[q];
      for (int c = 0; c < NPTS / 256; ++c) {
        int j = c * 256 + tid;
        int j3 = j * 3;
        float px = posb[j3 + 0], py = posb[j3 + 1], pz = posb[j3 + 2];
#pragma unroll
        for (int q = 0; q < QPB; ++q) {
          if (tr[q] != 0.f) {
            float dx = qx[q] - px, dy = qy[q] - py, dz = qz[q] - pz;
            float d2 = fmaf(dz, dz, fmaf(dy, dy, dx * dx));
            bool hit = d2 < tr[q];
            unsigned long long mask = __ballot(hit);
            if (mask) {
              if (hit) {
                unsigned int p = atomicAdd(&scnt[q], 1u);
                if (p < CAP) {
                  cbits[q][p] = __float_as_uint(d2);
                  cidx[q][p] = j;
                }
              }
            }
          }
        }
      }
      __syncthreads();
    }

    // rank selection -> s_idx[q*16+rank]; wave w handles query w
    {
      int q = w;
      int L = (int)scnt[q];
      if (L >= KNB && L <= CAP) {
        for (int i = lane; i < L; i += 64) {
          unsigned long long ki = ((unsigned long long)cbits[q][i] << 32) |
                                  (unsigned int)cidx[q][i];
          int rank = 0;
          for (int mm = 0; mm < L; ++mm) {
            unsigned long long km = ((unsigned long long)cbits[q][mm] << 32) |
                                    (unsigned int)cidx[q][mm];
            rank += km < ki;
          }
          if (rank < KNB) s_idx[q * KNB + rank] = cidx[q][i];
        }
      }
    }
    __syncthreads();

    // exact fallback (block-uniform branch; pathological only)
    for (int q = 0; q < QPB; ++q) {
      unsigned int n = scnt[q];
      if (n < KNB || n > CAP) {
        unsigned long long prev = 0ull;
        for (int r = 0; r < KNB; ++r) {
          unsigned long long best = ~0ull;
          for (int c = 0; c < NPTS / 256; ++c) {
            int j = c * 256 + tid;
            float dx = qx[q] - posb[j * 3 + 0];
            float dy = qy[q] - posb[j * 3 + 1];
            float dz = qz[q] - posb[j * 3 + 2];
            float d2 = fmaf(dz, dz, fmaf(dy, dy, dx * dx));
            unsigned long long key =
                ((unsigned long long)__float_as_uint(d2) << 32) |
                (unsigned int)j;
            bool ok = (r == 0) || (key > prev);
            best = (ok && key < best) ? key : best;
          }
#pragma unroll
          for (int off = 32; off > 0; off >>= 1) {
            unsigned long long o = __shfl_down(best, off);
            best = best < o ? best : o;
          }
          if (lane == 0) wmin[w] = best;
          __syncthreads();
          if (tid == 0) {
            unsigned long long m0 = wmin[0], m1 = wmin[1];
            unsigned long long m2 = wmin[2], m3 = wmin[3];
            unsigned long long a = m0 < m1 ? m0 : m1;
            unsigned long long d = m2 < m3 ? m2 : m3;
            a = a < d ? a : d;
            s_idx[q * KNB + r] = (int)(unsigned int)a;
            sprev[0] = a;
          }
          __syncthreads();
          prev = sprev[0];
          __syncthreads();
        }
      }
    }
  }
  __syncthreads();  // knn scratch dead; s_idx valid

  // ======================= attention phase =======================
  // wave w owns point g0+w; its 16 rows live in region rows 16w..16w+15
  unsigned short(*region)[72] = (unsigned short(*)[72])smem;        // 9216
  float(*s_rel)[16][3] = (float(*)[16][3])(smem + 9216);            // 768

  // staging: rel (parallel 16-lane gather)
  if (lane < 16) {
    int row = 16 * w + lane;
    int g = g0 + w;
    int jb = (b << 12) | s_idx[row];
    s_rel[w][lane][0] = pos[(size_t)g * 3 + 0] - pos[(size_t)jb * 3 + 0];
    s_rel[w][lane][1] = pos[(size_t)g * 3 + 1] - pos[(size_t)jb * 3 + 1];
    s_rel[w][lane][2] = pos[(size_t)g * 3 + 2] - pos[(size_t)jb * 3 + 2];
  }

  // phase2: e = relu(rel @ w_p1 + b_p1) -> region (s_e), wave rows
  {
    float w0 = w_p1[lane], w1 = w_p1[64 + lane], w2 = w_p1[128 + lane];
    float bp = b_p1[lane];
    for (int rl = 0; rl < 16; ++rl) {
      int row = 16 * w + rl;
      float rx = s_rel[w][rl][0], ry = s_rel[w][rl][1], rz = s_rel[w][rl][2];
      float e = fmaf(rz, w2, fmaf(ry, w1, fmaf(rx, w0, bp)));
      region[row][lane] = f2bf(fmaxf(e, 0.f));
    }
  }

  // phase3: pe MFMA + h epilogue; s_h overwrites s_e (frags in regs first)
  {
    bf16x8 ea0 = *(const bf16x8*)&region[16 * w + m][quad * 8];
    bf16x8 ea1 = *(const bf16x8*)&region[16 * w + m][32 + quad * 8];
#pragma unroll
    for (int nt = 0; nt < 4; ++nt) {
      bf16x8 b0 = *(const bf16x8*)(pkp + ((size_t)(nt * 2 + 0) * 64 + lane) * 8);
      bf16x8 b1 = *(const bf16x8*)(pkp + ((size_t)(nt * 2 + 1) * 64 + lane) * 8);
      int col = nt * 16 + m;
      float bp2 = b_p2[col];
      f32x4 acc = {0.f, 0.f, 0.f, 0.f};
      acc = MFMA16(ea0, b0, acc);
      acc = MFMA16(ea1, b1, acc);
      int g = g0 + w;
      float qv = qkv[(size_t)g * 192 + col];
#pragma unroll
      for (int i = 0; i < 4; ++i) {
        int row = 16 * w + quad * 4 + i;
        int jb = (b << 12) | s_idx[row];
        float kv = qkv[(size_t)jb * 192 + 64 + col];
        region[row][col] = f2bf(qv - kv + acc[i] + bp2);  // s_h
      }
    }
  }

  // v prefetch into registers (latency hidden behind GEMM1/2 below)
  float vreg[4][4];
#pragma unroll
  for (int i = 0; i < 4; ++i) {
    int row = 16 * w + quad * 4 + i;
    int jb = (b << 12) | s_idx[row];
    const float* vr = qkv + (size_t)jb * 192 + 128;
#pragma unroll
    for (int nt2 = 0; nt2 < 4; ++nt2) vreg[nt2][i] = vr[nt2 * 16 + m];
  }

  // phase4+5: chunked GEMM1 -> s_tc (aliases own s_h rows) -> GEMM2 acc
  bf16x8 ha0 = *(const bf16x8*)&region[16 * w + m][quad * 8];
  bf16x8 ha1 = *(const bf16x8*)&region[16 * w + m][32 + quad * 8];
  f32x4 acc2[4];
#pragma unroll
  for (int nt2 = 0; nt2 < 4; ++nt2) acc2[nt2] = (f32x4){0.f, 0.f, 0.f, 0.f};

  unsigned short(*s_tc)[72] = (unsigned short(*)[72])(smem + w * 2304);

#pragma unroll
  for (int c = 0; c < 4; ++c) {
#pragma unroll
    for (int ntc = 0; ntc < 4; ++ntc) {
      int nt = 4 * c + ntc;
      bf16x8 b0 = *(const bf16x8*)(pk1 + ((size_t)(nt * 2 + 0) * 64 + lane) * 8);
      bf16x8 b1 = *(const bf16x8*)(pk1 + ((size_t)(nt * 2 + 1) * 64 + lane) * 8);
      int coll = ntc * 16 + m;
      float ba = b_a1[nt * 16 + m];
      f32x4 t = {0.f, 0.f, 0.f, 0.f};
      t = MFMA16(ha0, b0, t);
      t = MFMA16(ha1, b1, t);
#pragma unroll
      for (int i = 0; i < 4; ++i)
        s_tc[quad * 4 + i][coll] = f2bf(fmaxf(t[i] + ba, 0.f));
    }
#pragma unroll
    for (int sub = 0; sub < 2; ++sub) {
      int ks = c * 2 + sub;
      bf16x8 a = *(const bf16x8*)&s_tc[m][sub * 32 + quad * 8];
#pragma unroll
      for (int nt2 = 0; nt2 < 4; ++nt2) {
        bf16x8 bb =
            *(const bf16x8*)(pk2 + ((size_t)(nt2 * 8 + ks) * 64 + lane) * 8);
        acc2[nt2] = MFMA16(a, bb, acc2[nt2]);
      }
    }
  }

  // phase6: softmax over k (quad shuffles) + v-weighted sum (v from vreg)
  float aggv[4];
#pragma unroll
  for (int nt2 = 0; nt2 < 4; ++nt2) {
    float ba2 = b_a2[nt2 * 16 + m];
    float sc[4];
#pragma unroll
    for (int i = 0; i < 4; ++i) sc[i] = acc2[nt2][i] + ba2;
    float mx = fmaxf(fmaxf(sc[0], sc[1]), fmaxf(sc[2], sc[3]));
    mx = fmaxf(mx, __shfl_xor(mx, 16));
    mx = fmaxf(mx, __shfl_xor(mx, 32));
    float ex[4], ss = 0.f;
#pragma unroll
    for (int i = 0; i < 4; ++i) {
      ex[i] = exp2f((sc[i] - mx) * 1.4426950408889634f);
      ss += ex[i];
    }
    ss += __shfl_xor(ss, 16);
    ss += __shfl_xor(ss, 32);
    float nu = 0.f;
#pragma unroll
    for (int i = 0; i < 4; ++i) nu = fmaf(ex[i], vreg[nt2][i], nu);
    nu += __shfl_xor(nu, 16);
    nu += __shfl_xor(nu, 32);
    aggv[nt2] = nu / ss;
  }
  __syncthreads();  // all waves done with region -> reuse for agg/red

  float* s_agg = (float*)smem;  // [4][64]
  if (quad == 0) {
#pragma unroll
    for (int nt2 = 0; nt2 < 4; ++nt2)
      s_agg[w * 64 + nt2 * 16 + m] = aggv[nt2];
  }
  __syncthreads();

  // fc: thread (r=w, c=lane) handles row w
  {
    int c = lane;
    float acc0 = b_fc[c];
    for (int d = 0; d < 64; ++d)
      acc0 = fmaf(s_agg[w * 64 + d], w_fc[d * 64 + c], acc0);
    y[(size_t)(g0 + w) * 64 + c] = acc0;
    float* s_red = (float*)(smem + 2048);
    float* s_red2 = (float*)(smem + 3072);
    s_red[w * 64 + c] = acc0;
    s_red2[w * 64 + c] = acc0 * acc0;
  }
  __syncthreads();
  if (tid < 64) {
    float* s_red = (float*)(smem + 2048);
    float* s_red2 = (float*)(smem + 3072);
    float s = s_red[tid] + s_red[64 + tid] + s_red[128 + tid] + s_red[192 + tid];
    float s2 =
        s_red2[tid] + s_red2[64 + tid] + s_red2[128 + tid] + s_red2[192 + tid];
    atomicAdd(&stats[tid], s);
    atomicAdd(&stats[64 + tid], s2);
  }
}

// ---------------------------------------------------------------------------
// Kernel 3: BN (batch stats) + relu + residual.
// ---------------------------------------------------------------------------
__global__ __launch_bounds__(256) void bn_kernel(
    const float* __restrict__ y, const float* __restrict__ x,
    const float* __restrict__ stats, const float* __restrict__ gamma,
    const float* __restrict__ beta, float* __restrict__ out) {
  size_t o = (size_t)blockIdx.x * 256 + threadIdx.x;
  int c = (int)(o & 63);
  const float inv_n = 1.f / 8192.f;
  float mean = stats[c] * inv_n;
  float var = stats[64 + c] * inv_n - mean * mean;
  float inv = rsqrtf(var + 1e-5f);
  float v = (y[o] - mean) * inv * gamma[c] + beta[c];
  out[o] = fmaxf(v, 0.f) + x[o];
}

// ---------------------------------------------------------------------------
extern "C" void kernel_launch(void* const* d_in, const int* in_sizes, int n_in,
                              void* d_out, int out_size, void* d_ws,
                              size_t ws_size, hipStream_t stream) {
  const float* x = (const float*)d_in[0];
  const float* pos = (const float*)d_in[1];
  const float* w_qkv = (const float*)d_in[2];
  const float* b_qkv = (const float*)d_in[3];
  const float* w_p1 = (const float*)d_in[4];
  const float* b_p1 = (const float*)d_in[5];
  const float* w_p2 = (const float*)d_in[6];
  const float* b_p2 = (const float*)d_in[7];
  const float* w_a1 = (const float*)d_in[8];
  const float* b_a1 = (const float*)d_in[9];
  const float* w_a2 = (const float*)d_in[10];
  const float* b_a2 = (const float*)d_in[11];
  const float* w_fc = (const float*)d_in[12];
  const float* b_fc = (const float*)d_in[13];
  const float* gamma = (const float*)d_in[14];
  const float* beta = (const float*)d_in[15];

  char* ws = (char*)d_ws;
  float* qkv = (float*)(ws + 0);                           // 6291456 B
  float* y = (float*)(ws + 8912896);                       // 2097152 B
  float* stats = (float*)(ws + 11010048);                  // 512 B
  unsigned short* pk1 = (unsigned short*)(ws + 11010560);  // 32768 B
  unsigned short* pk2 = (unsigned short*)(ws + 11043328);  // 32768 B
  unsigned short* pkp = (unsigned short*)(ws + 11076096);  // 8192 B

  hipLaunchKernelGGL(qkv_pack_kernel, dim3(273), dim3(256), 0, stream, x,
                     w_qkv, b_qkv, qkv, w_a1, w_a2, w_p2, pk1, pk2, pkp,
                     stats);
  hipLaunchKernelGGL(fused_kernel, dim3(2048), dim3(256), 0, stream, qkv, pos,
                     pk1, pk2, pkp, w_p1, b_p1, b_p2, b_a1, b_a2, w_fc, b_fc,
                     y, stats);
  hipLaunchKernelGGL(bn_kernel, dim3(2048), dim3(256), 0, stream, y, x, stats,
                     gamma, beta, (float*)d_out);
}

// Round 14
// 165.272 us; speedup vs baseline: 1.0538x; 1.0538x over previous
//
#include <hip/hip_runtime.h>
#include <hip/hip_bf16.h>
#include <math.h>

#define NPTS 4096
#define KNB 16
#define CAP 384
#define QPB 8   // points (=knn queries) per block

typedef __attribute__((ext_vector_type(8))) short bf16x8;
typedef __attribute__((ext_vector_type(4))) float f32x4;
#define MFMA16(a, b, c) __builtin_amdgcn_mfma_f32_16x16x32_bf16(a, b, c, 0, 0, 0)

__device__ __forceinline__ unsigned short f2bf(float f) {
  unsigned int u = __float_as_uint(f);
  unsigned int r = (u + 0x7fffu + ((u >> 16) & 1u)) >> 16;
  return (unsigned short)r;
}
__device__ __forceinline__ int cell1d(float v) {
  int c = (int)(v * 8.f);
  return c < 0 ? 0 : (c > 7 ? 7 : c);
}

// ---------------------------------------------------------------------------
// Kernel 1 "qkv_pack":
//   blocks [0,128)   qkv = x @ w_qkv + b_qkv via MFMA (64 rows/block, no LDS)
//   blocks [128,272) pack w_a1/w_a2/w_p2 -> bf16 MFMA B-frag order
//   blocks 272,273   build 8x8x8 cell grid for batch b=bid-272:
//                    counting-sort pos -> spos[] (x,y,z,idx), gstart[513]
//   block 274        zero stats
// ---------------------------------------------------------------------------
__global__ __launch_bounds__(256) void qkv_pack_kernel(
    const float* __restrict__ x, const float* __restrict__ w_qkv,
    const float* __restrict__ b_qkv, float* __restrict__ qkv,
    const float* __restrict__ w_a1, const float* __restrict__ w_a2,
    const float* __restrict__ w_p2, unsigned short* __restrict__ pk1,
    unsigned short* __restrict__ pk2, unsigned short* __restrict__ pkp,
    const float* __restrict__ pos, float4* __restrict__ spos,
    unsigned int* __restrict__ gstart, float* __restrict__ stats) {
  __shared__ unsigned int gcnt[512];
  __shared__ unsigned int gst[513];
  int tid = threadIdx.x, bid = blockIdx.x;

  if (bid == 274) {
    if (tid < 128) stats[tid] = 0.f;
    return;
  }
  if (bid >= 272) {  // grid build for batch b
    int b = bid - 272;
    const float* posb = pos + (size_t)b * NPTS * 3;
    for (int i = tid; i < 512; i += 256) gcnt[i] = 0;
    __syncthreads();
    for (int i = tid; i < NPTS; i += 256) {
      int cx = cell1d(posb[i * 3 + 0]);
      int cy = cell1d(posb[i * 3 + 1]);
      int cz = cell1d(posb[i * 3 + 2]);
      atomicAdd(&gcnt[(cx * 8 + cy) * 8 + cz], 1u);
    }
    __syncthreads();
    if (tid == 0) {
      unsigned int s = 0;
      for (int c = 0; c < 512; ++c) {
        gst[c] = s;
        s += gcnt[c];
      }
      gst[512] = s;
    }
    __syncthreads();
    for (int i = tid; i < 513; i += 256) gstart[b * 513 + i] = gst[i];
    for (int i = tid; i < 512; i += 256) gcnt[i] = 0;
    __syncthreads();
    for (int i = tid; i < NPTS; i += 256) {
      float px = posb[i * 3 + 0], py = posb[i * 3 + 1], pz = posb[i * 3 + 2];
      int cell = (cell1d(px) * 8 + cell1d(py)) * 8 + cell1d(pz);
      unsigned int p = atomicAdd(&gcnt[cell], 1u);
      float4 v;
      v.x = px; v.y = py; v.z = pz; v.w = __int_as_float(i);
      spos[(size_t)b * NPTS + gst[cell] + p] = v;
    }
    return;
  }
  if (bid >= 128) {
    int e = (bid - 128) * 256 + tid;
    if (e < 16384) {  // w_a1 [64][256]: KS=2, NT=16
      int j = e & 7, lane = (e >> 3) & 63, t = e >> 9;
      int ks = t & 1, nt = t >> 1;
      int k = ks * 32 + ((lane >> 4) << 3) + j, n = nt * 16 + (lane & 15);
      pk1[e] = f2bf(w_a1[k * 256 + n]);
    } else if (e < 32768) {  // w_a2 [256][64]: KS=8, NT=4
      int e2 = e - 16384;
      int j = e2 & 7, lane = (e2 >> 3) & 63, t = e2 >> 9;
      int ks = t & 7, nt = t >> 3;
      int k = ks * 32 + ((lane >> 4) << 3) + j, n = nt * 16 + (lane & 15);
      pk2[e2] = f2bf(w_a2[k * 64 + n]);
    } else if (e < 36864) {  // w_p2 [64][64]: KS=2, NT=4
      int e3 = e - 32768;
      int j = e3 & 7, lane = (e3 >> 3) & 63, t = e3 >> 9;
      int ks = t & 1, nt = t >> 1;
      int k = ks * 32 + ((lane >> 4) << 3) + j, n = nt * 16 + (lane & 15);
      pkp[e3] = f2bf(w_p2[k * 64 + n]);
    }
    return;
  }

  // qkv MFMA: wave w -> rows r0w..r0w+15
  int lane = tid & 63, w = tid >> 6;
  int m = lane & 15, quad = lane >> 4;
  int r0w = bid * 64 + w * 16;

  const float* xr = x + (size_t)(r0w + m) * 64;
  float xa[8], xb[8];
  *(float4*)&xa[0] = *(const float4*)(xr + quad * 8);
  *(float4*)&xa[4] = *(const float4*)(xr + quad * 8 + 4);
  *(float4*)&xb[0] = *(const float4*)(xr + 32 + quad * 8);
  *(float4*)&xb[4] = *(const float4*)(xr + 32 + quad * 8 + 4);
  bf16x8 a0, a1;
#pragma unroll
  for (int j = 0; j < 8; ++j) {
    a0[j] = (short)f2bf(xa[j]);
    a1[j] = (short)f2bf(xb[j]);
  }

#pragma unroll 4
  for (int nt = 0; nt < 12; ++nt) {
    int n = nt * 16 + m;
    int k0 = quad * 8;
    bf16x8 b0, b1;
#pragma unroll
    for (int j = 0; j < 8; ++j) {
      b0[j] = (short)f2bf(w_qkv[(size_t)(k0 + j) * 192 + n]);
      b1[j] = (short)f2bf(w_qkv[(size_t)(32 + k0 + j) * 192 + n]);
    }
    f32x4 acc = {0.f, 0.f, 0.f, 0.f};
    acc = MFMA16(a0, b0, acc);
    acc = MFMA16(a1, b1, acc);
    float bb = b_qkv[n];
#pragma unroll
    for (int i = 0; i < 4; ++i)
      qkv[(size_t)(r0w + quad * 4 + i) * 192 + n] = acc[i] + bb;
  }
}

// ---------------------------------------------------------------------------
// Kernel 2 "fused" (v5): per block = 8 points. Grid-accelerated KNN:
// wave w collects its 2 queries' candidates from +-1 cells (~216 cand,
// coverage of d<0.125 guaranteed), retry +-2 @ d<0.25 if count<16, exact
// full-scan fallback beyond that. Rank-select on (d2bits,idx) = identical
// output set+order to R12. Then R12's MFMA attention + fc + stats.
// ---------------------------------------------------------------------------
__global__ __launch_bounds__(256, 4) void fused_kernel(
    const float* __restrict__ qkv, const float* __restrict__ pos,
    const float4* __restrict__ spos, const unsigned int* __restrict__ gstart,
    const unsigned short* __restrict__ pk1,
    const unsigned short* __restrict__ pk2,
    const unsigned short* __restrict__ pkp, const float* __restrict__ w_p1,
    const float* __restrict__ b_p1, const float* __restrict__ b_p2,
    const float* __restrict__ b_a1, const float* __restrict__ b_a2,
    const float* __restrict__ w_fc, const float* __restrict__ b_fc,
    float* __restrict__ y, float* __restrict__ stats) {
  __shared__ __align__(16) char smem[25216];
  __shared__ int s_idx[128];

  int tid = threadIdx.x, lane = tid & 63, w = tid >> 6;
  int m = lane & 15, quad = lane >> 4;
  int g0 = blockIdx.x * QPB;
  int b = g0 >> 12;
  const float* posb = pos + (size_t)b * NPTS * 3;
  const float4* sposb = spos + (size_t)b * NPTS;
  const unsigned int* gsb = gstart + b * 513;

  // ======================= KNN phase (grid) =======================
  {
    unsigned int(*cbits)[CAP] = (unsigned int(*)[CAP])smem;            // 12288
    int(*cidx)[CAP] = (int(*)[CAP])(smem + 12288);                     // 12288
    unsigned long long* wmin = (unsigned long long*)(smem + 24576);    // 32
    unsigned int* scnt = (unsigned int*)(smem + 24608);                // 32
    unsigned long long* sprev = (unsigned long long*)(smem + 24640);   // 8

    float qx[QPB], qy[QPB], qz[QPB];
#pragma unroll
    for (int q = 0; q < QPB; ++q) {
      int i = (g0 + q) & (NPTS - 1);
      qx[q] = posb[i * 3 + 0];
      qy[q] = posb[i * 3 + 1];
      qz[q] = posb[i * 3 + 2];
    }
    if (lane == 0) {
      scnt[2 * w] = 0;
      scnt[2 * w + 1] = 0;
    }

    // wave w: collect for queries 2w, 2w+1 over +-R cells, threshold T
    for (int qq = 0; qq < 2; ++qq) {
      int q = 2 * w + qq;
      float qxx = qx[q], qyy = qy[q], qzz = qz[q];
      int cx = cell1d(qxx), cy = cell1d(qyy), cz = cell1d(qzz);
      float T = 0.015625f;  // d < 0.125 (= cell size): +-1 coverage
      int R = 1;
      for (int attempt = 0; attempt < 2; ++attempt) {
        int x0 = cx - R < 0 ? 0 : cx - R, x1 = cx + R > 7 ? 7 : cx + R;
        int y0 = cy - R < 0 ? 0 : cy - R, y1 = cy + R > 7 ? 7 : cy + R;
        int z0 = cz - R < 0 ? 0 : cz - R, z1 = cz + R > 7 ? 7 : cz + R;
        for (int xx = x0; xx <= x1; ++xx) {
          for (int yy = y0; yy <= y1; ++yy) {
            int rowc = (xx * 8 + yy) * 8;
            unsigned int s = gsb[rowc + z0];
            unsigned int e = gsb[rowc + z1 + 1];
            for (unsigned int i = s + lane; i < e; i += 64) {
              float4 p = sposb[i];
              float dx = qxx - p.x, dy = qyy - p.y, dz = qzz - p.z;
              float d2 = fmaf(dz, dz, fmaf(dy, dy, dx * dx));
              if (d2 < T) {
                unsigned int pp = atomicAdd(&scnt[q], 1u);
                if (pp < CAP) {
                  cbits[q][pp] = __float_as_uint(d2);
                  cidx[q][pp] = __float_as_int(p.w);
                }
              }
            }
          }
        }
        if (attempt == 0 && scnt[q] < KNB) {  // wave-uniform retry
          if (lane == 0) scnt[q] = 0;
          T = 0.0625f;  // d < 0.25: +-2 coverage
          R = 2;
        } else {
          break;
        }
      }
    }

    // rank selection -> s_idx[q*16+rank]; wave w handles queries 2w, 2w+1
    for (int qq = 0; qq < 2; ++qq) {
      int q = 2 * w + qq;
      int L = (int)scnt[q];
      if (L >= KNB && L <= CAP) {
        for (int i = lane; i < L; i += 64) {
          unsigned long long ki = ((unsigned long long)cbits[q][i] << 32) |
                                  (unsigned int)cidx[q][i];
          int rank = 0;
          for (int mm = 0; mm < L; ++mm) {
            unsigned long long km = ((unsigned long long)cbits[q][mm] << 32) |
                                    (unsigned int)cidx[q][mm];
            rank += km < ki;
          }
          if (rank < KNB) s_idx[q * KNB + rank] = cidx[q][i];
        }
      }
    }
    __syncthreads();

    // exact fallback (block-uniform branch; pathological only)
    for (int q = 0; q < QPB; ++q) {
      unsigned int n = scnt[q];
      if (n < KNB || n > CAP) {
        unsigned long long prev = 0ull;
        for (int r = 0; r < KNB; ++r) {
          unsigned long long best = ~0ull;
          for (int c = 0; c < NPTS / 256; ++c) {
            int j = c * 256 + tid;
            float dx = qx[q] - posb[j * 3 + 0];
            float dy = qy[q] - posb[j * 3 + 1];
            float dz = qz[q] - posb[j * 3 + 2];
            float d2 = fmaf(dz, dz, fmaf(dy, dy, dx * dx));
            unsigned long long key =
                ((unsigned long long)__float_as_uint(d2) << 32) |
                (unsigned int)j;
            bool ok = (r == 0) || (key > prev);
            best = (ok && key < best) ? key : best;
          }
#pragma unroll
          for (int off = 32; off > 0; off >>= 1) {
            unsigned long long o = __shfl_down(best, off);
            best = best < o ? best : o;
          }
          if (lane == 0) wmin[w] = best;
          __syncthreads();
          if (tid == 0) {
            unsigned long long m0 = wmin[0], m1 = wmin[1];
            unsigned long long m2 = wmin[2], m3 = wmin[3];
            unsigned long long a = m0 < m1 ? m0 : m1;
            unsigned long long d = m2 < m3 ? m2 : m3;
            a = a < d ? a : d;
            s_idx[q * KNB + r] = (int)(unsigned int)a;
            sprev[0] = a;
          }
          __syncthreads();
          prev = sprev[0];
          __syncthreads();
        }
      }
    }
  }
  __syncthreads();  // knn scratch dead; s_idx valid

  // ======================= attention phase (R12 verbatim) =======================
  unsigned short(*region)[72] = (unsigned short(*)[72])smem;        // 18432
  float(*s_rel)[32][3] = (float(*)[32][3])(smem + 18432);           // 1536

  if (lane < 32) {
    int row = 32 * w + lane;
    int p = lane >> 4;
    int g = g0 + 2 * w + p;
    int jb = (b << 12) | s_idx[row];
    s_rel[w][lane][0] = pos[(size_t)g * 3 + 0] - pos[(size_t)jb * 3 + 0];
    s_rel[w][lane][1] = pos[(size_t)g * 3 + 1] - pos[(size_t)jb * 3 + 1];
    s_rel[w][lane][2] = pos[(size_t)g * 3 + 2] - pos[(size_t)jb * 3 + 2];
  }

  {
    float w0 = w_p1[lane], w1 = w_p1[64 + lane], w2 = w_p1[128 + lane];
    float bp = b_p1[lane];
    for (int rl = 0; rl < 32; ++rl) {
      int row = 32 * w + rl;
      float rx = s_rel[w][rl][0], ry = s_rel[w][rl][1], rz = s_rel[w][rl][2];
      float e = fmaf(rz, w2, fmaf(ry, w1, fmaf(rx, w0, bp)));
      region[row][lane] = f2bf(fmaxf(e, 0.f));
    }
  }

  {
    bf16x8 ea0[2], ea1[2];
#pragma unroll
    for (int p = 0; p < 2; ++p) {
      ea0[p] = *(const bf16x8*)&region[32 * w + 16 * p + m][quad * 8];
      ea1[p] = *(const bf16x8*)&region[32 * w + 16 * p + m][32 + quad * 8];
    }
#pragma unroll
    for (int nt = 0; nt < 4; ++nt) {
      bf16x8 b0 = *(const bf16x8*)(pkp + ((size_t)(nt * 2 + 0) * 64 + lane) * 8);
      bf16x8 b1 = *(const bf16x8*)(pkp + ((size_t)(nt * 2 + 1) * 64 + lane) * 8);
      int col = nt * 16 + m;
      float bp2 = b_p2[col];
#pragma unroll
      for (int p = 0; p < 2; ++p) {
        f32x4 acc = {0.f, 0.f, 0.f, 0.f};
        acc = MFMA16(ea0[p], b0, acc);
        acc = MFMA16(ea1[p], b1, acc);
        int g = g0 + 2 * w + p;
        float qv = qkv[(size_t)g * 192 + col];
#pragma unroll
        for (int i = 0; i < 4; ++i) {
          int row = 32 * w + 16 * p + quad * 4 + i;
          int jb = (b << 12) | s_idx[row];
          float kv = qkv[(size_t)jb * 192 + 64 + col];
          region[row][col] = f2bf(qv - kv + acc[i] + bp2);  // s_h
        }
      }
    }
  }

  float vreg[2][4][4];
#pragma unroll
  for (int p = 0; p < 2; ++p)
#pragma unroll
    for (int i = 0; i < 4; ++i) {
      int row = 32 * w + 16 * p + quad * 4 + i;
      int jb = (b << 12) | s_idx[row];
      const float* vr = qkv + (size_t)jb * 192 + 128;
#pragma unroll
      for (int nt2 = 0; nt2 < 4; ++nt2) vreg[p][nt2][i] = vr[nt2 * 16 + m];
    }

  bf16x8 ha0[2], ha1[2];
#pragma unroll
  for (int p = 0; p < 2; ++p) {
    ha0[p] = *(const bf16x8*)&region[32 * w + 16 * p + m][quad * 8];
    ha1[p] = *(const bf16x8*)&region[32 * w + 16 * p + m][32 + quad * 8];
  }
  f32x4 acc2[2][4];
#pragma unroll
  for (int p = 0; p < 2; ++p)
#pragma unroll
    for (int nt2 = 0; nt2 < 4; ++nt2) acc2[p][nt2] = (f32x4){0.f, 0.f, 0.f, 0.f};

  unsigned short(*s_tc)[72] = (unsigned short(*)[72])(smem + w * 4608);

#pragma unroll
  for (int c = 0; c < 4; ++c) {
#pragma unroll
    for (int ntc = 0; ntc < 4; ++ntc) {
      int nt = 4 * c + ntc;
      bf16x8 b0 = *(const bf16x8*)(pk1 + ((size_t)(nt * 2 + 0) * 64 + lane) * 8);
      bf16x8 b1 = *(const bf16x8*)(pk1 + ((size_t)(nt * 2 + 1) * 64 + lane) * 8);
      int coll = ntc * 16 + m;
      float ba = b_a1[nt * 16 + m];
#pragma unroll
      for (int p = 0; p < 2; ++p) {
        f32x4 t = {0.f, 0.f, 0.f, 0.f};
        t = MFMA16(ha0[p], b0, t);
        t = MFMA16(ha1[p], b1, t);
#pragma unroll
        for (int i = 0; i < 4; ++i)
          s_tc[16 * p + quad * 4 + i][coll] = f2bf(fmaxf(t[i] + ba, 0.f));
      }
    }
#pragma unroll
    for (int sub = 0; sub < 2; ++sub) {
      int ks = c * 2 + sub;
      bf16x8 a[2];
#pragma unroll
      for (int p = 0; p < 2; ++p)
        a[p] = *(const bf16x8*)&s_tc[16 * p + m][sub * 32 + quad * 8];
#pragma unroll
      for (int nt2 = 0; nt2 < 4; ++nt2) {
        bf16x8 bb =
            *(const bf16x8*)(pk2 + ((size_t)(nt2 * 8 + ks) * 64 + lane) * 8);
#pragma unroll
        for (int p = 0; p < 2; ++p) acc2[p][nt2] = MFMA16(a[p], bb, acc2[p][nt2]);
      }
    }
  }

  float ba2[4];
#pragma unroll
  for (int nt2 = 0; nt2 < 4; ++nt2) ba2[nt2] = b_a2[nt2 * 16 + m];
  float aggv[2][4];
#pragma unroll
  for (int p = 0; p < 2; ++p) {
#pragma unroll
    for (int nt2 = 0; nt2 < 4; ++nt2) {
      float sc[4];
#pragma unroll
      for (int i = 0; i < 4; ++i) sc[i] = acc2[p][nt2][i] + ba2[nt2];
      float mx = fmaxf(fmaxf(sc[0], sc[1]), fmaxf(sc[2], sc[3]));
      mx = fmaxf(mx, __shfl_xor(mx, 16));
      mx = fmaxf(mx, __shfl_xor(mx, 32));
      float ex[4], ss = 0.f;
#pragma unroll
      for (int i = 0; i < 4; ++i) {
        ex[i] = exp2f((sc[i] - mx) * 1.4426950408889634f);
        ss += ex[i];
      }
      ss += __shfl_xor(ss, 16);
      ss += __shfl_xor(ss, 32);
      float nu = 0.f;
#pragma unroll
      for (int i = 0; i < 4; ++i) nu = fmaf(ex[i], vreg[p][nt2][i], nu);
      nu += __shfl_xor(nu, 16);
      nu += __shfl_xor(nu, 32);
      aggv[p][nt2] = nu / ss;
    }
  }
  __syncthreads();  // all waves done with region -> reuse for agg/red

  float* s_agg = (float*)smem;  // [8][64]
  if (quad == 0) {
#pragma unroll
    for (int p = 0; p < 2; ++p)
#pragma unroll
      for (int nt2 = 0; nt2 < 4; ++nt2)
        s_agg[(2 * w + p) * 64 + nt2 * 16 + m] = aggv[p][nt2];
  }
  __syncthreads();

  {
    int c = lane, r = w;
    float acc0 = b_fc[c], acc1 = b_fc[c];
    for (int d = 0; d < 64; ++d) {
      float wv = w_fc[d * 64 + c];
      acc0 = fmaf(s_agg[r * 64 + d], wv, acc0);
      acc1 = fmaf(s_agg[(r + 4) * 64 + d], wv, acc1);
    }
    y[(size_t)(g0 + r) * 64 + c] = acc0;
    y[(size_t)(g0 + r + 4) * 64 + c] = acc1;
    float* s_red = (float*)(smem + 2048);
    float* s_red2 = (float*)(smem + 3072);
    s_red[w * 64 + c] = acc0 + acc1;
    s_red2[w * 64 + c] = acc0 * acc0 + acc1 * acc1;
  }
  __syncthreads();
  if (tid < 64) {
    float* s_red = (float*)(smem + 2048);
    float* s_red2 = (float*)(smem + 3072);
    float s = s_red[tid] + s_red[64 + tid] + s_red[128 + tid] + s_red[192 + tid];
    float s2 =
        s_red2[tid] + s_red2[64 + tid] + s_red2[128 + tid] + s_red2[192 + tid];
    atomicAdd(&stats[tid], s);
    atomicAdd(&stats[64 + tid], s2);
  }
}

// ---------------------------------------------------------------------------
// Kernel 3: BN (batch stats) + relu + residual.
// ---------------------------------------------------------------------------
__global__ __launch_bounds__(256) void bn_kernel(
    const float* __restrict__ y, const float* __restrict__ x,
    const float* __restrict__ stats, const float* __restrict__ gamma,
    const float* __restrict__ beta, float* __restrict__ out) {
  size_t o = (size_t)blockIdx.x * 256 + threadIdx.x;
  int c = (int)(o & 63);
  const float inv_n = 1.f / 8192.f;
  float mean = stats[c] * inv_n;
  float var = stats[64 + c] * inv_n - mean * mean;
  float inv = rsqrtf(var + 1e-5f);
  float v = (y[o] - mean) * inv * gamma[c] + beta[c];
  out[o] = fmaxf(v, 0.f) + x[o];
}

// ---------------------------------------------------------------------------
extern "C" void kernel_launch(void* const* d_in, const int* in_sizes, int n_in,
                              void* d_out, int out_size, void* d_ws,
                              size_t ws_size, hipStream_t stream) {
  const float* x = (const float*)d_in[0];
  const float* pos = (const float*)d_in[1];
  const float* w_qkv = (const float*)d_in[2];
  const float* b_qkv = (const float*)d_in[3];
  const float* w_p1 = (const float*)d_in[4];
  const float* b_p1 = (const float*)d_in[5];
  const float* w_p2 = (const float*)d_in[6];
  const float* b_p2 = (const float*)d_in[7];
  const float* w_a1 = (const float*)d_in[8];
  const float* b_a1 = (const float*)d_in[9];
  const float* w_a2 = (const float*)d_in[10];
  const float* b_a2 = (const float*)d_in[11];
  const float* w_fc = (const float*)d_in[12];
  const float* b_fc = (const float*)d_in[13];
  const float* gamma = (const float*)d_in[14];
  const float* beta = (const float*)d_in[15];

  char* ws = (char*)d_ws;
  float* qkv = (float*)(ws + 0);                           // 6291456 B
  float4* spos = (float4*)(ws + 6291456);                  // 131072 B
  unsigned int* gstart = (unsigned int*)(ws + 6422528);    // 4104 B
  float* y = (float*)(ws + 8912896);                       // 2097152 B
  float* stats = (float*)(ws + 11010048);                  // 512 B
  unsigned short* pk1 = (unsigned short*)(ws + 11010560);  // 32768 B
  unsigned short* pk2 = (unsigned short*)(ws + 11043328);  // 32768 B
  unsigned short* pkp = (unsigned short*)(ws + 11076096);  // 8192 B

  hipLaunchKernelGGL(qkv_pack_kernel, dim3(275), dim3(256), 0, stream, x,
                     w_qkv, b_qkv, qkv, w_a1, w_a2, w_p2, pk1, pk2, pkp, pos,
                     spos, gstart, stats);
  hipLaunchKernelGGL(fused_kernel, dim3(1024), dim3(256), 0, stream, qkv, pos,
                     spos, gstart, pk1, pk2, pkp, w_p1, b_p1, b_p2, b_a1, b_a2,
                     w_fc, b_fc, y, stats);
  hipLaunchKernelGGL(bn_kernel, dim3(2048), dim3(256), 0, stream, y, x, stats,
                     gamma, beta, (float*)d_out);
}

// Round 16
// 150.111 us; speedup vs baseline: 1.1603x; 1.1010x over previous
//
#include <hip/hip_runtime.h>
#include <hip/hip_bf16.h>
#include <math.h>

#define NPTS 4096
#define KNB 16
#define CAP 384
#define QPB 8   // points (=knn queries) per block

typedef __attribute__((ext_vector_type(8))) short bf16x8;
typedef __attribute__((ext_vector_type(4))) float f32x4;
#define MFMA16(a, b, c) __builtin_amdgcn_mfma_f32_16x16x32_bf16(a, b, c, 0, 0, 0)

__device__ __forceinline__ unsigned short f2bf(float f) {
  unsigned int u = __float_as_uint(f);
  unsigned int r = (u + 0x7fffu + ((u >> 16) & 1u)) >> 16;
  return (unsigned short)r;
}

// ---------------------------------------------------------------------------
// Kernel 1 "qkv_pack":
//   blocks [0,128)   qkv = x @ w_qkv + b_qkv via MFMA (64 rows/block, no LDS)
//   blocks [128,272) pack w_a1/w_a2/w_p2 -> bf16 MFMA B-frag order
//   blocks 272,273   pos4[b][i] = (x,y,z,0) for batch b  (KNN scan vec-load)
//   block 274        zero stats
// ---------------------------------------------------------------------------
__global__ __launch_bounds__(256) void qkv_pack_kernel(
    const float* __restrict__ x, const float* __restrict__ w_qkv,
    const float* __restrict__ b_qkv, float* __restrict__ qkv,
    const float* __restrict__ w_a1, const float* __restrict__ w_a2,
    const float* __restrict__ w_p2, unsigned short* __restrict__ pk1,
    unsigned short* __restrict__ pk2, unsigned short* __restrict__ pkp,
    const float* __restrict__ pos, float4* __restrict__ pos4,
    float* __restrict__ stats) {
  int tid = threadIdx.x, bid = blockIdx.x;

  if (bid == 274) {
    if (tid < 128) stats[tid] = 0.f;
    return;
  }
  if (bid >= 272) {  // pos4 build for batch b
    int b = bid - 272;
    const float* posb = pos + (size_t)b * NPTS * 3;
    for (int i = tid; i < NPTS; i += 256) {
      float4 v;
      v.x = posb[i * 3 + 0];
      v.y = posb[i * 3 + 1];
      v.z = posb[i * 3 + 2];
      v.w = 0.f;
      pos4[(size_t)b * NPTS + i] = v;
    }
    return;
  }
  if (bid >= 128) {
    int e = (bid - 128) * 256 + tid;
    if (e < 16384) {  // w_a1 [64][256]: KS=2, NT=16
      int j = e & 7, lane = (e >> 3) & 63, t = e >> 9;
      int ks = t & 1, nt = t >> 1;
      int k = ks * 32 + ((lane >> 4) << 3) + j, n = nt * 16 + (lane & 15);
      pk1[e] = f2bf(w_a1[k * 256 + n]);
    } else if (e < 32768) {  // w_a2 [256][64]: KS=8, NT=4
      int e2 = e - 16384;
      int j = e2 & 7, lane = (e2 >> 3) & 63, t = e2 >> 9;
      int ks = t & 7, nt = t >> 3;
      int k = ks * 32 + ((lane >> 4) << 3) + j, n = nt * 16 + (lane & 15);
      pk2[e2] = f2bf(w_a2[k * 64 + n]);
    } else if (e < 36864) {  // w_p2 [64][64]: KS=2, NT=4
      int e3 = e - 32768;
      int j = e3 & 7, lane = (e3 >> 3) & 63, t = e3 >> 9;
      int ks = t & 1, nt = t >> 1;
      int k = ks * 32 + ((lane >> 4) << 3) + j, n = nt * 16 + (lane & 15);
      pkp[e3] = f2bf(w_p2[k * 64 + n]);
    }
    return;
  }

  // qkv MFMA: wave w -> rows r0w..r0w+15
  int lane = tid & 63, w = tid >> 6;
  int m = lane & 15, quad = lane >> 4;
  int r0w = bid * 64 + w * 16;

  const float* xr = x + (size_t)(r0w + m) * 64;
  float xa[8], xb[8];
  *(float4*)&xa[0] = *(const float4*)(xr + quad * 8);
  *(float4*)&xa[4] = *(const float4*)(xr + quad * 8 + 4);
  *(float4*)&xb[0] = *(const float4*)(xr + 32 + quad * 8);
  *(float4*)&xb[4] = *(const float4*)(xr + 32 + quad * 8 + 4);
  bf16x8 a0, a1;
#pragma unroll
  for (int j = 0; j < 8; ++j) {
    a0[j] = (short)f2bf(xa[j]);
    a1[j] = (short)f2bf(xb[j]);
  }

#pragma unroll 4
  for (int nt = 0; nt < 12; ++nt) {
    int n = nt * 16 + m;
    int k0 = quad * 8;
    bf16x8 b0, b1;
#pragma unroll
    for (int j = 0; j < 8; ++j) {
      b0[j] = (short)f2bf(w_qkv[(size_t)(k0 + j) * 192 + n]);
      b1[j] = (short)f2bf(w_qkv[(size_t)(32 + k0 + j) * 192 + n]);
    }
    f32x4 acc = {0.f, 0.f, 0.f, 0.f};
    acc = MFMA16(a0, b0, acc);
    acc = MFMA16(a1, b1, acc);
    float bb = b_qkv[n];
#pragma unroll
    for (int i = 0; i < 4; ++i)
      qkv[(size_t)(r0w + quad * 4 + i) * 192 + n] = acc[i] + bb;
  }
}

// ---------------------------------------------------------------------------
// Kernel 2 "fused" (R12 + pos4 vec-load scan): per block = 8 points.
// One-pass KNN (collect d2<T2 from float4 pos; retry; exact fallback) ->
// s_idx, then MFMA attention + fc + stats. LDS ~25.2 KB, (256,4).
// ---------------------------------------------------------------------------
__global__ __launch_bounds__(256, 4) void fused_kernel(
    const float* __restrict__ qkv, const float* __restrict__ pos,
    const float4* __restrict__ pos4, const unsigned short* __restrict__ pk1,
    const unsigned short* __restrict__ pk2,
    const unsigned short* __restrict__ pkp, const float* __restrict__ w_p1,
    const float* __restrict__ b_p1, const float* __restrict__ b_p2,
    const float* __restrict__ b_a1, const float* __restrict__ b_a2,
    const float* __restrict__ w_fc, const float* __restrict__ b_fc,
    float* __restrict__ y, float* __restrict__ stats) {
  __shared__ __align__(16) char smem[25216];
  __shared__ int s_idx[128];

  int tid = threadIdx.x, lane = tid & 63, w = tid >> 6;
  int m = lane & 15, quad = lane >> 4;
  int g0 = blockIdx.x * QPB;
  int b = g0 >> 12;
  const float* posb = pos + (size_t)b * NPTS * 3;
  const float4* pos4b = pos4 + (size_t)b * NPTS;

  // ======================= KNN phase =======================
  {
    unsigned int(*cbits)[CAP] = (unsigned int(*)[CAP])smem;            // 12288
    int(*cidx)[CAP] = (int(*)[CAP])(smem + 12288);                     // 12288
    unsigned long long* wmin = (unsigned long long*)(smem + 24576);    // 32
    float* sretry = (float*)(smem + 24608);                            // 32
    unsigned int* scnt = (unsigned int*)(smem + 24640);                // 32
    unsigned long long* sprev = (unsigned long long*)(smem + 24672);   // 8
    int* sany = (int*)(smem + 24680);                                  // 4

    float qx[QPB], qy[QPB], qz[QPB];
#pragma unroll
    for (int q = 0; q < QPB; ++q) {
      int i = (g0 + q) & (NPTS - 1);
      qx[q] = posb[i * 3 + 0];
      qy[q] = posb[i * 3 + 1];
      qz[q] = posb[i * 3 + 2];
    }
    if (tid < QPB) scnt[tid] = 0;
    if (tid == 0) sany[0] = 0;
    __syncthreads();

    const float T2 = 0.015625f;  // d < 0.125; expected count ~33
    for (int c = 0; c < NPTS / 256; ++c) {
      int j = c * 256 + tid;
      float4 pj = pos4b[j];
      float px = pj.x, py = pj.y, pz = pj.z;
#pragma unroll
      for (int q = 0; q < QPB; ++q) {
        float dx = qx[q] - px, dy = qy[q] - py, dz = qz[q] - pz;
        float d2 = fmaf(dz, dz, fmaf(dy, dy, dx * dx));
        bool hit = d2 < T2;
        unsigned long long mask = __ballot(hit);
        if (mask) {  // wave-uniform skip (~60% of iterations have no hits)
          if (hit) {
            unsigned int p = atomicAdd(&scnt[q], 1u);
            if (p < CAP) {
              cbits[q][p] = __float_as_uint(d2);
              cidx[q][p] = j;
            }
          }
        }
      }
    }
    __syncthreads();

    if (tid < QPB) {
      int q = tid;
      unsigned int n = scnt[q];
      float nt = 0.f;
      if (n < KNB) nt = 0.0625f;            // widen: d < 0.25
      else if (n > CAP) nt = 0.00390625f;   // narrow: d < 0.0625
      sretry[q] = nt;
      if (nt != 0.f) {
        scnt[q] = 0;
        sany[0] = 1;
      }
    }
    __syncthreads();

    if (sany[0]) {  // rare; block-uniform
      float tr[QPB];
#pragma unroll
      for (int q = 0; q < QPB; ++q) tr[q] = sretry[q];
      for (int c = 0; c < NPTS / 256; ++c) {
        int j = c * 256 + tid;
        float4 pj = pos4b[j];
        float px = pj.x, py = pj.y, pz = pj.z;
#pragma unroll
        for (int q = 0; q < QPB; ++q) {
          if (tr[q] != 0.f) {
            float dx = qx[q] - px, dy = qy[q] - py, dz = qz[q] - pz;
            float d2 = fmaf(dz, dz, fmaf(dy, dy, dx * dx));
            bool hit = d2 < tr[q];
            unsigned long long mask = __ballot(hit);
            if (mask) {
              if (hit) {
                unsigned int p = atomicAdd(&scnt[q], 1u);
                if (p < CAP) {
                  cbits[q][p] = __float_as_uint(d2);
                  cidx[q][p] = j;
                }
              }
            }
          }
        }
      }
      __syncthreads();
    }

    // rank selection -> s_idx[q*16+rank]; wave w handles queries 2w, 2w+1
    for (int qq = 0; qq < 2; ++qq) {
      int q = w * 2 + qq;
      int L = (int)scnt[q];
      if (L >= KNB && L <= CAP) {
        for (int i = lane; i < L; i += 64) {
          unsigned long long ki = ((unsigned long long)cbits[q][i] << 32) |
                                  (unsigned int)cidx[q][i];
          int rank = 0;
          for (int mm = 0; mm < L; ++mm) {
            unsigned long long km = ((unsigned long long)cbits[q][mm] << 32) |
                                    (unsigned int)cidx[q][mm];
            rank += km < ki;
          }
          if (rank < KNB) s_idx[q * KNB + rank] = cidx[q][i];
        }
      }
    }
    __syncthreads();

    // exact fallback (block-uniform branch; pathological only)
    for (int q = 0; q < QPB; ++q) {
      unsigned int n = scnt[q];
      if (n < KNB || n > CAP) {
        unsigned long long prev = 0ull;
        for (int r = 0; r < KNB; ++r) {
          unsigned long long best = ~0ull;
          for (int c = 0; c < NPTS / 256; ++c) {
            int j = c * 256 + tid;
            float4 pj = pos4b[j];
            float dx = qx[q] - pj.x;
            float dy = qy[q] - pj.y;
            float dz = qz[q] - pj.z;
            float d2 = fmaf(dz, dz, fmaf(dy, dy, dx * dx));
            unsigned long long key =
                ((unsigned long long)__float_as_uint(d2) << 32) |
                (unsigned int)j;
            bool ok = (r == 0) || (key > prev);
            best = (ok && key < best) ? key : best;
          }
#pragma unroll
          for (int off = 32; off > 0; off >>= 1) {
            unsigned long long o = __shfl_down(best, off);
            best = best < o ? best : o;
          }
          if (lane == 0) wmin[w] = best;
          __syncthreads();
          if (tid == 0) {
            unsigned long long m0 = wmin[0], m1 = wmin[1];
            unsigned long long m2 = wmin[2], m3 = wmin[3];
            unsigned long long a = m0 < m1 ? m0 : m1;
            unsigned long long d = m2 < m3 ? m2 : m3;
            a = a < d ? a : d;
            s_idx[q * KNB + r] = (int)(unsigned int)a;
            sprev[0] = a;
          }
          __syncthreads();
          prev = sprev[0];
          __syncthreads();
        }
      }
    }
  }
  __syncthreads();  // knn scratch dead; s_idx valid

  // ======================= attention phase =======================
  unsigned short(*region)[72] = (unsigned short(*)[72])smem;        // 18432
  float(*s_rel)[32][3] = (float(*)[32][3])(smem + 18432);           // 1536

  // staging: rel (parallel 32-lane gather)
  if (lane < 32) {
    int row = 32 * w + lane;
    int p = lane >> 4;
    int g = g0 + 2 * w + p;
    int jb = (b << 12) | s_idx[row];
    s_rel[w][lane][0] = pos[(size_t)g * 3 + 0] - pos[(size_t)jb * 3 + 0];
    s_rel[w][lane][1] = pos[(size_t)g * 3 + 1] - pos[(size_t)jb * 3 + 1];
    s_rel[w][lane][2] = pos[(size_t)g * 3 + 2] - pos[(size_t)jb * 3 + 2];
  }

  // phase2: e = relu(rel @ w_p1 + b_p1) -> region (s_e), wave rows
  {
    float w0 = w_p1[lane], w1 = w_p1[64 + lane], w2 = w_p1[128 + lane];
    float bp = b_p1[lane];
    for (int rl = 0; rl < 32; ++rl) {
      int row = 32 * w + rl;
      float rx = s_rel[w][rl][0], ry = s_rel[w][rl][1], rz = s_rel[w][rl][2];
      float e = fmaf(rz, w2, fmaf(ry, w1, fmaf(rx, w0, bp)));
      region[row][lane] = f2bf(fmaxf(e, 0.f));
    }
  }

  // phase3: pe MFMA + h epilogue; s_h overwrites s_e (frags in regs first)
  {
    bf16x8 ea0[2], ea1[2];
#pragma unroll
    for (int p = 0; p < 2; ++p) {
      ea0[p] = *(const bf16x8*)&region[32 * w + 16 * p + m][quad * 8];
      ea1[p] = *(const bf16x8*)&region[32 * w + 16 * p + m][32 + quad * 8];
    }
#pragma unroll
    for (int nt = 0; nt < 4; ++nt) {
      bf16x8 b0 = *(const bf16x8*)(pkp + ((size_t)(nt * 2 + 0) * 64 + lane) * 8);
      bf16x8 b1 = *(const bf16x8*)(pkp + ((size_t)(nt * 2 + 1) * 64 + lane) * 8);
      int col = nt * 16 + m;
      float bp2 = b_p2[col];
#pragma unroll
      for (int p = 0; p < 2; ++p) {
        f32x4 acc = {0.f, 0.f, 0.f, 0.f};
        acc = MFMA16(ea0[p], b0, acc);
        acc = MFMA16(ea1[p], b1, acc);
        int g = g0 + 2 * w + p;
        float qv = qkv[(size_t)g * 192 + col];
#pragma unroll
        for (int i = 0; i < 4; ++i) {
          int row = 32 * w + 16 * p + quad * 4 + i;
          int jb = (b << 12) | s_idx[row];
          float kv = qkv[(size_t)jb * 192 + 64 + col];
          region[row][col] = f2bf(qv - kv + acc[i] + bp2);  // s_h
        }
      }
    }
  }

  // v prefetch into registers (latency hidden behind GEMM1/2 below)
  float vreg[2][4][4];
#pragma unroll
  for (int p = 0; p < 2; ++p)
#pragma unroll
    for (int i = 0; i < 4; ++i) {
      int row = 32 * w + 16 * p + quad * 4 + i;
      int jb = (b << 12) | s_idx[row];
      const float* vr = qkv + (size_t)jb * 192 + 128;
#pragma unroll
      for (int nt2 = 0; nt2 < 4; ++nt2) vreg[p][nt2][i] = vr[nt2 * 16 + m];
    }

  // phase4+5: chunked GEMM1 -> s_tc (aliases own s_h rows) -> GEMM2 acc
  bf16x8 ha0[2], ha1[2];
#pragma unroll
  for (int p = 0; p < 2; ++p) {
    ha0[p] = *(const bf16x8*)&region[32 * w + 16 * p + m][quad * 8];
    ha1[p] = *(const bf16x8*)&region[32 * w + 16 * p + m][32 + quad * 8];
  }
  f32x4 acc2[2][4];
#pragma unroll
  for (int p = 0; p < 2; ++p)
#pragma unroll
    for (int nt2 = 0; nt2 < 4; ++nt2) acc2[p][nt2] = (f32x4){0.f, 0.f, 0.f, 0.f};

  unsigned short(*s_tc)[72] = (unsigned short(*)[72])(smem + w * 4608);

#pragma unroll
  for (int c = 0; c < 4; ++c) {
#pragma unroll
    for (int ntc = 0; ntc < 4; ++ntc) {
      int nt = 4 * c + ntc;
      bf16x8 b0 = *(const bf16x8*)(pk1 + ((size_t)(nt * 2 + 0) * 64 + lane) * 8);
      bf16x8 b1 = *(const bf16x8*)(pk1 + ((size_t)(nt * 2 + 1) * 64 + lane) * 8);
      int coll = ntc * 16 + m;
      float ba = b_a1[nt * 16 + m];
#pragma unroll
      for (int p = 0; p < 2; ++p) {
        f32x4 t = {0.f, 0.f, 0.f, 0.f};
        t = MFMA16(ha0[p], b0, t);
        t = MFMA16(ha1[p], b1, t);
#pragma unroll
        for (int i = 0; i < 4; ++i)
          s_tc[16 * p + quad * 4 + i][coll] = f2bf(fmaxf(t[i] + ba, 0.f));
      }
    }
#pragma unroll
    for (int sub = 0; sub < 2; ++sub) {
      int ks = c * 2 + sub;
      bf16x8 a[2];
#pragma unroll
      for (int p = 0; p < 2; ++p)
        a[p] = *(const bf16x8*)&s_tc[16 * p + m][sub * 32 + quad * 8];
#pragma unroll
      for (int nt2 = 0; nt2 < 4; ++nt2) {
        bf16x8 bb =
            *(const bf16x8*)(pk2 + ((size_t)(nt2 * 8 + ks) * 64 + lane) * 8);
#pragma unroll
        for (int p = 0; p < 2; ++p) acc2[p][nt2] = MFMA16(a[p], bb, acc2[p][nt2]);
      }
    }
  }

  // phase6: softmax over k (quad shuffles) + v-weighted sum (v from vreg)
  float ba2[4];
#pragma unroll
  for (int nt2 = 0; nt2 < 4; ++nt2) ba2[nt2] = b_a2[nt2 * 16 + m];
  float aggv[2][4];
#pragma unroll
  for (int p = 0; p < 2; ++p) {
#pragma unroll
    for (int nt2 = 0; nt2 < 4; ++nt2) {
      float sc[4];
#pragma unroll
      for (int i = 0; i < 4; ++i) sc[i] = acc2[p][nt2][i] + ba2[nt2];
      float mx = fmaxf(fmaxf(sc[0], sc[1]), fmaxf(sc[2], sc[3]));
      mx = fmaxf(mx, __shfl_xor(mx, 16));
      mx = fmaxf(mx, __shfl_xor(mx, 32));
      float ex[4], ss = 0.f;
#pragma unroll
      for (int i = 0; i < 4; ++i) {
        ex[i] = exp2f((sc[i] - mx) * 1.4426950408889634f);
        ss += ex[i];
      }
      ss += __shfl_xor(ss, 16);
      ss += __shfl_xor(ss, 32);
      float nu = 0.f;
#pragma unroll
      for (int i = 0; i < 4; ++i) nu = fmaf(ex[i], vreg[p][nt2][i], nu);
      nu += __shfl_xor(nu, 16);
      nu += __shfl_xor(nu, 32);
      aggv[p][nt2] = nu / ss;
    }
  }
  __syncthreads();  // all waves done with region -> reuse for agg/red

  float* s_agg = (float*)smem;  // [8][64]
  if (quad == 0) {
#pragma unroll
    for (int p = 0; p < 2; ++p)
#pragma unroll
      for (int nt2 = 0; nt2 < 4; ++nt2)
        s_agg[(2 * w + p) * 64 + nt2 * 16 + m] = aggv[p][nt2];
  }
  __syncthreads();

  // fc: thread (r=w, c=lane) handles rows w and w+4
  {
    int c = lane, r = w;
    float acc0 = b_fc[c], acc1 = b_fc[c];
    for (int d = 0; d < 64; ++d) {
      float wv = w_fc[d * 64 + c];
      acc0 = fmaf(s_agg[r * 64 + d], wv, acc0);
      acc1 = fmaf(s_agg[(r + 4) * 64 + d], wv, acc1);
    }
    y[(size_t)(g0 + r) * 64 + c] = acc0;
    y[(size_t)(g0 + r + 4) * 64 + c] = acc1;
    float* s_red = (float*)(smem + 2048);
    float* s_red2 = (float*)(smem + 3072);
    s_red[w * 64 + c] = acc0 + acc1;
    s_red2[w * 64 + c] = acc0 * acc0 + acc1 * acc1;
  }
  __syncthreads();
  if (tid < 64) {
    float* s_red = (float*)(smem + 2048);
    float* s_red2 = (float*)(smem + 3072);
    float s = s_red[tid] + s_red[64 + tid] + s_red[128 + tid] + s_red[192 + tid];
    float s2 =
        s_red2[tid] + s_red2[64 + tid] + s_red2[128 + tid] + s_red2[192 + tid];
    atomicAdd(&stats[tid], s);
    atomicAdd(&stats[64 + tid], s2);
  }
}

// ---------------------------------------------------------------------------
// Kernel 3: BN (batch stats) + relu + residual, float4-vectorized.
// ---------------------------------------------------------------------------
__global__ __launch_bounds__(256) void bn_kernel(
    const float4* __restrict__ y, const float4* __restrict__ x,
    const float* __restrict__ stats, const float* __restrict__ gamma,
    const float* __restrict__ beta, float4* __restrict__ out) {
  size_t o = (size_t)blockIdx.x * 256 + threadIdx.x;  // float4 index
  int c0 = (int)((o * 4) & 63);
  const float inv_n = 1.f / 8192.f;
  float4 yv = y[o], xv = x[o], ov;
  float vv[4] = {yv.x, yv.y, yv.z, yv.w};
  float xx[4] = {xv.x, xv.y, xv.z, xv.w};
  float rr[4];
#pragma unroll
  for (int i = 0; i < 4; ++i) {
    int c = c0 + i;
    float mean = stats[c] * inv_n;
    float var = stats[64 + c] * inv_n - mean * mean;
    float inv = rsqrtf(var + 1e-5f);
    float v = (vv[i] - mean) * inv * gamma[c] + beta[c];
    rr[i] = fmaxf(v, 0.f) + xx[i];
  }
  ov.x = rr[0]; ov.y = rr[1]; ov.z = rr[2]; ov.w = rr[3];
  out[o] = ov;
}

// ---------------------------------------------------------------------------
extern "C" void kernel_launch(void* const* d_in, const int* in_sizes, int n_in,
                              void* d_out, int out_size, void* d_ws,
                              size_t ws_size, hipStream_t stream) {
  const float* x = (const float*)d_in[0];
  const float* pos = (const float*)d_in[1];
  const float* w_qkv = (const float*)d_in[2];
  const float* b_qkv = (const float*)d_in[3];
  const float* w_p1 = (const float*)d_in[4];
  const float* b_p1 = (const float*)d_in[5];
  const float* w_p2 = (const float*)d_in[6];
  const float* b_p2 = (const float*)d_in[7];
  const float* w_a1 = (const float*)d_in[8];
  const float* b_a1 = (const float*)d_in[9];
  const float* w_a2 = (const float*)d_in[10];
  const float* b_a2 = (const float*)d_in[11];
  const float* w_fc = (const float*)d_in[12];
  const float* b_fc = (const float*)d_in[13];
  const float* gamma = (const float*)d_in[14];
  const float* beta = (const float*)d_in[15];

  char* ws = (char*)d_ws;
  float* qkv = (float*)(ws + 0);                           // 6291456 B
  float4* pos4 = (float4*)(ws + 6291456);                  // 131072 B
  float* y = (float*)(ws + 8912896);                       // 2097152 B
  float* stats = (float*)(ws + 11010048);                  // 512 B
  unsigned short* pk1 = (unsigned short*)(ws + 11010560);  // 32768 B
  unsigned short* pk2 = (unsigned short*)(ws + 11043328);  // 32768 B
  unsigned short* pkp = (unsigned short*)(ws + 11076096);  // 8192 B

  hipLaunchKernelGGL(qkv_pack_kernel, dim3(275), dim3(256), 0, stream, x,
                     w_qkv, b_qkv, qkv, w_a1, w_a2, w_p2, pk1, pk2, pkp, pos,
                     pos4, stats);
  hipLaunchKernelGGL(fused_kernel, dim3(1024), dim3(256), 0, stream, qkv, pos,
                     pos4, pk1, pk2, pkp, w_p1, b_p1, b_p2, b_a1, b_a2, w_fc,
                     b_fc, y, stats);
  hipLaunchKernelGGL(bn_kernel, dim3(512), dim3(256), 0, stream, (float4*)y,
                     (const float4*)x, stats, gamma, beta, (float4*)d_out);
}

// Round 17
// 149.319 us; speedup vs baseline: 1.1664x; 1.0053x over previous
//
#include <hip/hip_runtime.h>
#include <hip/hip_bf16.h>
#include <math.h>

#define NPTS 4096
#define KNB 16
#define CAP 384
#define QPB 8   // points (=knn queries) per block

typedef __attribute__((ext_vector_type(8))) short bf16x8;
typedef __attribute__((ext_vector_type(4))) float f32x4;
#define MFMA16(a, b, c) __builtin_amdgcn_mfma_f32_16x16x32_bf16(a, b, c, 0, 0, 0)

__device__ __forceinline__ unsigned short f2bf(float f) {
  unsigned int u = __float_as_uint(f);
  unsigned int r = (u + 0x7fffu + ((u >> 16) & 1u)) >> 16;
  return (unsigned short)r;
}

// ---------------------------------------------------------------------------
// Kernel 1 "qkv_pack" (R12 verbatim):
//   blocks [0,128)   qkv = x @ w_qkv + b_qkv via MFMA (64 rows/block, no LDS)
//   blocks [128,272) pack w_a1/w_a2/w_p2 -> bf16 MFMA B-frag order
//   block 272        zero stats
// ---------------------------------------------------------------------------
__global__ __launch_bounds__(256) void qkv_pack_kernel(
    const float* __restrict__ x, const float* __restrict__ w_qkv,
    const float* __restrict__ b_qkv, float* __restrict__ qkv,
    const float* __restrict__ w_a1, const float* __restrict__ w_a2,
    const float* __restrict__ w_p2, unsigned short* __restrict__ pk1,
    unsigned short* __restrict__ pk2, unsigned short* __restrict__ pkp,
    float* __restrict__ stats) {
  int tid = threadIdx.x, bid = blockIdx.x;

  if (bid == 272) {
    if (tid < 128) stats[tid] = 0.f;
    return;
  }
  if (bid >= 128) {
    int e = (bid - 128) * 256 + tid;
    if (e < 16384) {  // w_a1 [64][256]: KS=2, NT=16
      int j = e & 7, lane = (e >> 3) & 63, t = e >> 9;
      int ks = t & 1, nt = t >> 1;
      int k = ks * 32 + ((lane >> 4) << 3) + j, n = nt * 16 + (lane & 15);
      pk1[e] = f2bf(w_a1[k * 256 + n]);
    } else if (e < 32768) {  // w_a2 [256][64]: KS=8, NT=4
      int e2 = e - 16384;
      int j = e2 & 7, lane = (e2 >> 3) & 63, t = e2 >> 9;
      int ks = t & 7, nt = t >> 3;
      int k = ks * 32 + ((lane >> 4) << 3) + j, n = nt * 16 + (lane & 15);
      pk2[e2] = f2bf(w_a2[k * 64 + n]);
    } else if (e < 36864) {  // w_p2 [64][64]: KS=2, NT=4
      int e3 = e - 32768;
      int j = e3 & 7, lane = (e3 >> 3) & 63, t = e3 >> 9;
      int ks = t & 1, nt = t >> 1;
      int k = ks * 32 + ((lane >> 4) << 3) + j, n = nt * 16 + (lane & 15);
      pkp[e3] = f2bf(w_p2[k * 64 + n]);
    }
    return;
  }

  // qkv MFMA: wave w -> rows r0w..r0w+15
  int lane = tid & 63, w = tid >> 6;
  int m = lane & 15, quad = lane >> 4;
  int r0w = bid * 64 + w * 16;

  const float* xr = x + (size_t)(r0w + m) * 64;
  float xa[8], xb[8];
  *(float4*)&xa[0] = *(const float4*)(xr + quad * 8);
  *(float4*)&xa[4] = *(const float4*)(xr + quad * 8 + 4);
  *(float4*)&xb[0] = *(const float4*)(xr + 32 + quad * 8);
  *(float4*)&xb[4] = *(const float4*)(xr + 32 + quad * 8 + 4);
  bf16x8 a0, a1;
#pragma unroll
  for (int j = 0; j < 8; ++j) {
    a0[j] = (short)f2bf(xa[j]);
    a1[j] = (short)f2bf(xb[j]);
  }

#pragma unroll 4
  for (int nt = 0; nt < 12; ++nt) {
    int n = nt * 16 + m;
    int k0 = quad * 8;
    bf16x8 b0, b1;
#pragma unroll
    for (int j = 0; j < 8; ++j) {
      b0[j] = (short)f2bf(w_qkv[(size_t)(k0 + j) * 192 + n]);
      b1[j] = (short)f2bf(w_qkv[(size_t)(32 + k0 + j) * 192 + n]);
    }
    f32x4 acc = {0.f, 0.f, 0.f, 0.f};
    acc = MFMA16(a0, b0, acc);
    acc = MFMA16(a1, b1, acc);
    float bb = b_qkv[n];
#pragma unroll
    for (int i = 0; i < 4; ++i)
      qkv[(size_t)(r0w + quad * 4 + i) * 192 + n] = acc[i] + bb;
  }
}

// ---------------------------------------------------------------------------
// Kernel 2 "fused" (R12 verbatim — best measured at 59.3 us): per block =
// 8 points. One-pass KNN (scalar pos scan) -> s_idx, MFMA attention, v in
// 32 VGPRs, fc + stats. LDS ~25.2 KB, __launch_bounds__(256,4).
// ---------------------------------------------------------------------------
__global__ __launch_bounds__(256, 4) void fused_kernel(
    const float* __restrict__ qkv, const float* __restrict__ pos,
    const unsigned short* __restrict__ pk1,
    const unsigned short* __restrict__ pk2,
    const unsigned short* __restrict__ pkp, const float* __restrict__ w_p1,
    const float* __restrict__ b_p1, const float* __restrict__ b_p2,
    const float* __restrict__ b_a1, const float* __restrict__ b_a2,
    const float* __restrict__ w_fc, const float* __restrict__ b_fc,
    float* __restrict__ y, float* __restrict__ stats) {
  __shared__ __align__(16) char smem[25216];
  __shared__ int s_idx[128];

  int tid = threadIdx.x, lane = tid & 63, w = tid >> 6;
  int m = lane & 15, quad = lane >> 4;
  int g0 = blockIdx.x * QPB;
  int b = g0 >> 12;
  const float* posb = pos + (size_t)b * NPTS * 3;

  // ======================= KNN phase =======================
  {
    unsigned int(*cbits)[CAP] = (unsigned int(*)[CAP])smem;            // 12288
    int(*cidx)[CAP] = (int(*)[CAP])(smem + 12288);                     // 12288
    unsigned long long* wmin = (unsigned long long*)(smem + 24576);    // 32
    float* sretry = (float*)(smem + 24608);                            // 32
    unsigned int* scnt = (unsigned int*)(smem + 24640);                // 32
    unsigned long long* sprev = (unsigned long long*)(smem + 24672);   // 8
    int* sany = (int*)(smem + 24680);                                  // 4

    float qx[QPB], qy[QPB], qz[QPB];
#pragma unroll
    for (int q = 0; q < QPB; ++q) {
      int i = (g0 + q) & (NPTS - 1);
      qx[q] = posb[i * 3 + 0];
      qy[q] = posb[i * 3 + 1];
      qz[q] = posb[i * 3 + 2];
    }
    if (tid < QPB) scnt[tid] = 0;
    if (tid == 0) sany[0] = 0;
    __syncthreads();

    const float T2 = 0.015625f;  // d < 0.125; expected count ~33
    for (int c = 0; c < NPTS / 256; ++c) {
      int j = c * 256 + tid;
      int j3 = j * 3;
      float px = posb[j3 + 0], py = posb[j3 + 1], pz = posb[j3 + 2];
#pragma unroll
      for (int q = 0; q < QPB; ++q) {
        float dx = qx[q] - px, dy = qy[q] - py, dz = qz[q] - pz;
        float d2 = fmaf(dz, dz, fmaf(dy, dy, dx * dx));
        bool hit = d2 < T2;
        unsigned long long mask = __ballot(hit);
        if (mask) {  // wave-uniform skip (~60% of iterations have no hits)
          if (hit) {
            unsigned int p = atomicAdd(&scnt[q], 1u);
            if (p < CAP) {
              cbits[q][p] = __float_as_uint(d2);
              cidx[q][p] = j;
            }
          }
        }
      }
    }
    __syncthreads();

    if (tid < QPB) {
      int q = tid;
      unsigned int n = scnt[q];
      float nt = 0.f;
      if (n < KNB) nt = 0.0625f;            // widen: d < 0.25
      else if (n > CAP) nt = 0.00390625f;   // narrow: d < 0.0625
      sretry[q] = nt;
      if (nt != 0.f) {
        scnt[q] = 0;
        sany[0] = 1;
      }
    }
    __syncthreads();

    if (sany[0]) {  // rare; block-uniform
      float tr[QPB];
#pragma unroll
      for (int q = 0; q < QPB; ++q) tr[q] = sretry[q];
      for (int c = 0; c < NPTS / 256; ++c) {
        int j = c * 256 + tid;
        int j3 = j * 3;
        float px = posb[j3 + 0], py = posb[j3 + 1], pz = posb[j3 + 2];
#pragma unroll
        for (int q = 0; q < QPB; ++q) {
          if (tr[q] != 0.f) {
            float dx = qx[q] - px, dy = qy[q] - py, dz = qz[q] - pz;
            float d2 = fmaf(dz, dz, fmaf(dy, dy, dx * dx));
            bool hit = d2 < tr[q];
            unsigned long long mask = __ballot(hit);
            if (mask) {
              if (hit) {
                unsigned int p = atomicAdd(&scnt[q], 1u);
                if (p < CAP) {
                  cbits[q][p] = __float_as_uint(d2);
                  cidx[q][p] = j;
                }
              }
            }
          }
        }
      }
      __syncthreads();
    }

    // rank selection -> s_idx[q*16+rank]; wave w handles queries 2w, 2w+1
    for (int qq = 0; qq < 2; ++qq) {
      int q = w * 2 + qq;
      int L = (int)scnt[q];
      if (L >= KNB && L <= CAP) {
        for (int i = lane; i < L; i += 64) {
          unsigned long long ki = ((unsigned long long)cbits[q][i] << 32) |
                                  (unsigned int)cidx[q][i];
          int rank = 0;
          for (int mm = 0; mm < L; ++mm) {
            unsigned long long km = ((unsigned long long)cbits[q][mm] << 32) |
                                    (unsigned int)cidx[q][mm];
            rank += km < ki;
          }
          if (rank < KNB) s_idx[q * KNB + rank] = cidx[q][i];
        }
      }
    }
    __syncthreads();

    // exact fallback (block-uniform branch; pathological only)
    for (int q = 0; q < QPB; ++q) {
      unsigned int n = scnt[q];
      if (n < KNB || n > CAP) {
        unsigned long long prev = 0ull;
        for (int r = 0; r < KNB; ++r) {
          unsigned long long best = ~0ull;
          for (int c = 0; c < NPTS / 256; ++c) {
            int j = c * 256 + tid;
            float dx = qx[q] - posb[j * 3 + 0];
            float dy = qy[q] - posb[j * 3 + 1];
            float dz = qz[q] - posb[j * 3 + 2];
            float d2 = fmaf(dz, dz, fmaf(dy, dy, dx * dx));
            unsigned long long key =
                ((unsigned long long)__float_as_uint(d2) << 32) |
                (unsigned int)j;
            bool ok = (r == 0) || (key > prev);
            best = (ok && key < best) ? key : best;
          }
#pragma unroll
          for (int off = 32; off > 0; off >>= 1) {
            unsigned long long o = __shfl_down(best, off);
            best = best < o ? best : o;
          }
          if (lane == 0) wmin[w] = best;
          __syncthreads();
          if (tid == 0) {
            unsigned long long m0 = wmin[0], m1 = wmin[1];
            unsigned long long m2 = wmin[2], m3 = wmin[3];
            unsigned long long a = m0 < m1 ? m0 : m1;
            unsigned long long d = m2 < m3 ? m2 : m3;
            a = a < d ? a : d;
            s_idx[q * KNB + r] = (int)(unsigned int)a;
            sprev[0] = a;
          }
          __syncthreads();
          prev = sprev[0];
          __syncthreads();
        }
      }
    }
  }
  __syncthreads();  // knn scratch dead; s_idx valid

  // ======================= attention phase =======================
  unsigned short(*region)[72] = (unsigned short(*)[72])smem;        // 18432
  float(*s_rel)[32][3] = (float(*)[32][3])(smem + 18432);           // 1536

  // staging: rel (parallel 32-lane gather)
  if (lane < 32) {
    int row = 32 * w + lane;
    int p = lane >> 4;
    int g = g0 + 2 * w + p;
    int jb = (b << 12) | s_idx[row];
    s_rel[w][lane][0] = pos[(size_t)g * 3 + 0] - pos[(size_t)jb * 3 + 0];
    s_rel[w][lane][1] = pos[(size_t)g * 3 + 1] - pos[(size_t)jb * 3 + 1];
    s_rel[w][lane][2] = pos[(size_t)g * 3 + 2] - pos[(size_t)jb * 3 + 2];
  }

  // phase2: e = relu(rel @ w_p1 + b_p1) -> region (s_e), wave rows
  {
    float w0 = w_p1[lane], w1 = w_p1[64 + lane], w2 = w_p1[128 + lane];
    float bp = b_p1[lane];
    for (int rl = 0; rl < 32; ++rl) {
      int row = 32 * w + rl;
      float rx = s_rel[w][rl][0], ry = s_rel[w][rl][1], rz = s_rel[w][rl][2];
      float e = fmaf(rz, w2, fmaf(ry, w1, fmaf(rx, w0, bp)));
      region[row][lane] = f2bf(fmaxf(e, 0.f));
    }
  }

  // phase3: pe MFMA + h epilogue; s_h overwrites s_e (frags in regs first)
  {
    bf16x8 ea0[2], ea1[2];
#pragma unroll
    for (int p = 0; p < 2; ++p) {
      ea0[p] = *(const bf16x8*)&region[32 * w + 16 * p + m][quad * 8];
      ea1[p] = *(const bf16x8*)&region[32 * w + 16 * p + m][32 + quad * 8];
    }
#pragma unroll
    for (int nt = 0; nt < 4; ++nt) {
      bf16x8 b0 = *(const bf16x8*)(pkp + ((size_t)(nt * 2 + 0) * 64 + lane) * 8);
      bf16x8 b1 = *(const bf16x8*)(pkp + ((size_t)(nt * 2 + 1) * 64 + lane) * 8);
      int col = nt * 16 + m;
      float bp2 = b_p2[col];
#pragma unroll
      for (int p = 0; p < 2; ++p) {
        f32x4 acc = {0.f, 0.f, 0.f, 0.f};
        acc = MFMA16(ea0[p], b0, acc);
        acc = MFMA16(ea1[p], b1, acc);
        int g = g0 + 2 * w + p;
        float qv = qkv[(size_t)g * 192 + col];
#pragma unroll
        for (int i = 0; i < 4; ++i) {
          int row = 32 * w + 16 * p + quad * 4 + i;
          int jb = (b << 12) | s_idx[row];
          float kv = qkv[(size_t)jb * 192 + 64 + col];
          region[row][col] = f2bf(qv - kv + acc[i] + bp2);  // s_h
        }
      }
    }
  }

  // v prefetch into registers (latency hidden behind GEMM1/2 below)
  float vreg[2][4][4];
#pragma unroll
  for (int p = 0; p < 2; ++p)
#pragma unroll
    for (int i = 0; i < 4; ++i) {
      int row = 32 * w + 16 * p + quad * 4 + i;
      int jb = (b << 12) | s_idx[row];
      const float* vr = qkv + (size_t)jb * 192 + 128;
#pragma unroll
      for (int nt2 = 0; nt2 < 4; ++nt2) vreg[p][nt2][i] = vr[nt2 * 16 + m];
    }

  // phase4+5: chunked GEMM1 -> s_tc (aliases own s_h rows) -> GEMM2 acc
  bf16x8 ha0[2], ha1[2];
#pragma unroll
  for (int p = 0; p < 2; ++p) {
    ha0[p] = *(const bf16x8*)&region[32 * w + 16 * p + m][quad * 8];
    ha1[p] = *(const bf16x8*)&region[32 * w + 16 * p + m][32 + quad * 8];
  }
  f32x4 acc2[2][4];
#pragma unroll
  for (int p = 0; p < 2; ++p)
#pragma unroll
    for (int nt2 = 0; nt2 < 4; ++nt2) acc2[p][nt2] = (f32x4){0.f, 0.f, 0.f, 0.f};

  unsigned short(*s_tc)[72] = (unsigned short(*)[72])(smem + w * 4608);

#pragma unroll
  for (int c = 0; c < 4; ++c) {
#pragma unroll
    for (int ntc = 0; ntc < 4; ++ntc) {
      int nt = 4 * c + ntc;
      bf16x8 b0 = *(const bf16x8*)(pk1 + ((size_t)(nt * 2 + 0) * 64 + lane) * 8);
      bf16x8 b1 = *(const bf16x8*)(pk1 + ((size_t)(nt * 2 + 1) * 64 + lane) * 8);
      int coll = ntc * 16 + m;
      float ba = b_a1[nt * 16 + m];
#pragma unroll
      for (int p = 0; p < 2; ++p) {
        f32x4 t = {0.f, 0.f, 0.f, 0.f};
        t = MFMA16(ha0[p], b0, t);
        t = MFMA16(ha1[p], b1, t);
#pragma unroll
        for (int i = 0; i < 4; ++i)
          s_tc[16 * p + quad * 4 + i][coll] = f2bf(fmaxf(t[i] + ba, 0.f));
      }
    }
#pragma unroll
    for (int sub = 0; sub < 2; ++sub) {
      int ks = c * 2 + sub;
      bf16x8 a[2];
#pragma unroll
      for (int p = 0; p < 2; ++p)
        a[p] = *(const bf16x8*)&s_tc[16 * p + m][sub * 32 + quad * 8];
#pragma unroll
      for (int nt2 = 0; nt2 < 4; ++nt2) {
        bf16x8 bb =
            *(const bf16x8*)(pk2 + ((size_t)(nt2 * 8 + ks) * 64 + lane) * 8);
#pragma unroll
        for (int p = 0; p < 2; ++p) acc2[p][nt2] = MFMA16(a[p], bb, acc2[p][nt2]);
      }
    }
  }

  // phase6: softmax over k (quad shuffles) + v-weighted sum (v from vreg)
  float ba2[4];
#pragma unroll
  for (int nt2 = 0; nt2 < 4; ++nt2) ba2[nt2] = b_a2[nt2 * 16 + m];
  float aggv[2][4];
#pragma unroll
  for (int p = 0; p < 2; ++p) {
#pragma unroll
    for (int nt2 = 0; nt2 < 4; ++nt2) {
      float sc[4];
#pragma unroll
      for (int i = 0; i < 4; ++i) sc[i] = acc2[p][nt2][i] + ba2[nt2];
      float mx = fmaxf(fmaxf(sc[0], sc[1]), fmaxf(sc[2], sc[3]));
      mx = fmaxf(mx, __shfl_xor(mx, 16));
      mx = fmaxf(mx, __shfl_xor(mx, 32));
      float ex[4], ss = 0.f;
#pragma unroll
      for (int i = 0; i < 4; ++i) {
        ex[i] = exp2f((sc[i] - mx) * 1.4426950408889634f);
        ss += ex[i];
      }
      ss += __shfl_xor(ss, 16);
      ss += __shfl_xor(ss, 32);
      float nu = 0.f;
#pragma unroll
      for (int i = 0; i < 4; ++i) nu = fmaf(ex[i], vreg[p][nt2][i], nu);
      nu += __shfl_xor(nu, 16);
      nu += __shfl_xor(nu, 32);
      aggv[p][nt2] = nu / ss;
    }
  }
  __syncthreads();  // all waves done with region -> reuse for agg/red

  float* s_agg = (float*)smem;  // [8][64]
  if (quad == 0) {
#pragma unroll
    for (int p = 0; p < 2; ++p)
#pragma unroll
      for (int nt2 = 0; nt2 < 4; ++nt2)
        s_agg[(2 * w + p) * 64 + nt2 * 16 + m] = aggv[p][nt2];
  }
  __syncthreads();

  // fc: thread (r=w, c=lane) handles rows w and w+4
  {
    int c = lane, r = w;
    float acc0 = b_fc[c], acc1 = b_fc[c];
    for (int d = 0; d < 64; ++d) {
      float wv = w_fc[d * 64 + c];
      acc0 = fmaf(s_agg[r * 64 + d], wv, acc0);
      acc1 = fmaf(s_agg[(r + 4) * 64 + d], wv, acc1);
    }
    y[(size_t)(g0 + r) * 64 + c] = acc0;
    y[(size_t)(g0 + r + 4) * 64 + c] = acc1;
    float* s_red = (float*)(smem + 2048);
    float* s_red2 = (float*)(smem + 3072);
    s_red[w * 64 + c] = acc0 + acc1;
    s_red2[w * 64 + c] = acc0 * acc0 + acc1 * acc1;
  }
  __syncthreads();
  if (tid < 64) {
    float* s_red = (float*)(smem + 2048);
    float* s_red2 = (float*)(smem + 3072);
    float s = s_red[tid] + s_red[64 + tid] + s_red[128 + tid] + s_red[192 + tid];
    float s2 =
        s_red2[tid] + s_red2[64 + tid] + s_red2[128 + tid] + s_red2[192 + tid];
    atomicAdd(&stats[tid], s);
    atomicAdd(&stats[64 + tid], s2);
  }
}

// ---------------------------------------------------------------------------
// Kernel 3: BN (batch stats) + relu + residual, float4-vectorized (R16).
// ---------------------------------------------------------------------------
__global__ __launch_bounds__(256) void bn_kernel(
    const float4* __restrict__ y, const float4* __restrict__ x,
    const float* __restrict__ stats, const float* __restrict__ gamma,
    const float* __restrict__ beta, float4* __restrict__ out) {
  size_t o = (size_t)blockIdx.x * 256 + threadIdx.x;  // float4 index
  int c0 = (int)((o * 4) & 63);
  const float inv_n = 1.f / 8192.f;
  float4 yv = y[o], xv = x[o], ov;
  float vv[4] = {yv.x, yv.y, yv.z, yv.w};
  float xx[4] = {xv.x, xv.y, xv.z, xv.w};
  float rr[4];
#pragma unroll
  for (int i = 0; i < 4; ++i) {
    int c = c0 + i;
    float mean = stats[c] * inv_n;
    float var = stats[64 + c] * inv_n - mean * mean;
    float inv = rsqrtf(var + 1e-5f);
    float v = (vv[i] - mean) * inv * gamma[c] + beta[c];
    rr[i] = fmaxf(v, 0.f) + xx[i];
  }
  ov.x = rr[0]; ov.y = rr[1]; ov.z = rr[2]; ov.w = rr[3];
  out[o] = ov;
}

// ---------------------------------------------------------------------------
extern "C" void kernel_launch(void* const* d_in, const int* in_sizes, int n_in,
                              void* d_out, int out_size, void* d_ws,
                              size_t ws_size, hipStream_t stream) {
  const float* x = (const float*)d_in[0];
  const float* pos = (const float*)d_in[1];
  const float* w_qkv = (const float*)d_in[2];
  const float* b_qkv = (const float*)d_in[3];
  const float* w_p1 = (const float*)d_in[4];
  const float* b_p1 = (const float*)d_in[5];
  const float* w_p2 = (const float*)d_in[6];
  const float* b_p2 = (const float*)d_in[7];
  const float* w_a1 = (const float*)d_in[8];
  const float* b_a1 = (const float*)d_in[9];
  const float* w_a2 = (const float*)d_in[10];
  const float* b_a2 = (const float*)d_in[11];
  const float* w_fc = (const float*)d_in[12];
  const float* b_fc = (const float*)d_in[13];
  const float* gamma = (const float*)d_in[14];
  const float* beta = (const float*)d_in[15];

  char* ws = (char*)d_ws;
  float* qkv = (float*)(ws + 0);                           // 6291456 B
  float* y = (float*)(ws + 8912896);                       // 2097152 B
  float* stats = (float*)(ws + 11010048);                  // 512 B
  unsigned short* pk1 = (unsigned short*)(ws + 11010560);  // 32768 B
  unsigned short* pk2 = (unsigned short*)(ws + 11043328);  // 32768 B
  unsigned short* pkp = (unsigned short*)(ws + 11076096);  // 8192 B

  hipLaunchKernelGGL(qkv_pack_kernel, dim3(273), dim3(256), 0, stream, x,
                     w_qkv, b_qkv, qkv, w_a1, w_a2, w_p2, pk1, pk2, pkp,
                     stats);
  hipLaunchKernelGGL(fused_kernel, dim3(1024), dim3(256), 0, stream, qkv, pos,
                     pk1, pk2, pkp, w_p1, b_p1, b_p2, b_a1, b_a2, w_fc, b_fc,
                     y, stats);
  hipLaunchKernelGGL(bn_kernel, dim3(512), dim3(256), 0, stream, (const float4*)y,
                     (const float4*)x, stats, gamma, beta, (float4*)d_out);
}